// Round 4
// baseline (286.542 us; speedup 1.0000x reference)
//
#include <hip/hip_runtime.h>

// ---------------------------------------------------------------------------
// GIN: 3 x (bucket gather-sum + (x+agg)@W + b, relu) + MLP head, bf16 MFMA.
// r4: - gather latency chain broken: coalesced slot-index load (lane l reads
//       sl[l]) + __shfl broadcast -> all row loads independent.
//     - 32-row tiles (1563 blocks) -> ~24 waves/CU for latency hiding.
//     - 6 dispatches (cursor zero folded into prep, f2b+fill merged).
// ---------------------------------------------------------------------------

typedef short short8 __attribute__((ext_vector_type(8)));
typedef float v4f __attribute__((ext_vector_type(4)));

__device__ inline unsigned short f2bf(float f) {
  union { float f; unsigned int u; } c; c.f = f;
  unsigned int u = c.u;
  return (unsigned short)((u + 0x7fffu + ((u >> 16) & 1u)) >> 16);  // RNE
}
__device__ inline float bfbits2f(unsigned int hi) {
  union { unsigned int u; float f; } c; c.u = hi; return c.f;
}
__device__ inline unsigned int pack2(float a, float b) {
  return (unsigned int)f2bf(a) | ((unsigned int)f2bf(b) << 16);
}
__device__ inline void add8(float* s, uint4 v) {
  s[0] += bfbits2f(v.x << 16); s[1] += bfbits2f(v.x & 0xffff0000u);
  s[2] += bfbits2f(v.y << 16); s[3] += bfbits2f(v.y & 0xffff0000u);
  s[4] += bfbits2f(v.z << 16); s[5] += bfbits2f(v.z & 0xffff0000u);
  s[6] += bfbits2f(v.w << 16); s[7] += bfbits2f(v.w & 0xffff0000u);
}

// ------------------------- setup kernels -----------------------------------

// all 5 weights: transpose + fp32->bf16 (+ zero-pad Wm2 cols 10..15);
// also zeroes cursor[n].
__global__ __launch_bounds__(256) void prep_weights(
    const float* __restrict__ W0, const float* __restrict__ W1, const float* __restrict__ W2,
    const float* __restrict__ Wm1, const float* __restrict__ Wm2,
    unsigned short* __restrict__ W0T, unsigned short* __restrict__ W1T,
    unsigned short* __restrict__ W2T, unsigned short* __restrict__ Wm1T,
    unsigned short* __restrict__ Wm2T, int* __restrict__ cursor, int n) {
  int i = blockIdx.x * 256 + threadIdx.x;
  if (i < n) cursor[i] = 0;
  if (i < 49152) {                       // 3 x [128,128] -> [128n][128k]
    int w = i / 16384, r = i % 16384;
    int nn = r >> 7, k = r & 127;
    const float* W = (w == 0) ? W0 : (w == 1) ? W1 : W2;
    unsigned short* O = (w == 0) ? W0T : (w == 1) ? W1T : W2T;
    O[r] = f2bf(W[k * 128 + nn]);
  } else if (i < 49152 + 32768) {        // Wm1 [128,256] -> [256n][128k]
    int r = i - 49152;
    int nn = r >> 7, k = r & 127;
    Wm1T[r] = f2bf(Wm1[k * 256 + nn]);
  } else if (i < 49152 + 32768 + 4096) { // Wm2 [256,10] -> [16n][256k], pad 0
    int r = i - 49152 - 32768;
    int nn = r >> 8, k = r & 255;
    Wm2T[r] = (nn < 10) ? f2bf(Wm2[k * 10 + nn]) : (unsigned short)0;
  }
}

// fp32 x [N,128] -> bf16 (8 elems/thread) AND bucket build
// slots[dst*128 + p] = src (order arbitrary; sums commute).
__global__ __launch_bounds__(256) void f2b_fill(
    const float* __restrict__ in, unsigned short* __restrict__ out, int n8,
    const int* __restrict__ src, const int* __restrict__ dst,
    int* __restrict__ cursor, int* __restrict__ slots, int E) {
  int i = blockIdx.x * 256 + threadIdx.x;
  if (i < n8) {
    const float4* p = (const float4*)in;
    float4 a = p[2 * (size_t)i], b = p[2 * (size_t)i + 1];
    uint4 o;
    o.x = pack2(a.x, a.y); o.y = pack2(a.z, a.w);
    o.z = pack2(b.x, b.y); o.w = pack2(b.z, b.w);
    ((uint4*)out)[i] = o;
  }
  if (i < E) {
    int d = dst[i];
    int p = atomicAdd(&cursor[d], 1);
    slots[((size_t)d << 7) + p] = src[i];
  }
}

// ------------------------- fused layer -------------------------------------
// Per 32-node block: gather-sum rows into LDS (bf16), then
// C[32,128] = relu((x+agg) @ BT^T + bias). 4 waves in 2x2, wave 16m x 64n.
// Gather: 16-lane groups; slot indices loaded coalesced (lane l -> sl[l]),
// broadcast via __shfl so row loads are independent (latency-chain depth 3).
__global__ __launch_bounds__(256) void fused_layer(
    const unsigned short* __restrict__ X, const int* __restrict__ cnt,
    const int* __restrict__ slots, const unsigned short* __restrict__ BT,
    const float* __restrict__ bias, unsigned short* __restrict__ C, int M) {
  __shared__ __align__(16) unsigned short As[32 * 136];
  const int tid = threadIdx.x;
  const int l = tid & 15, g = tid >> 4;
  const int lane = tid & 63;
  const int gb = lane & 48;  // group base within wave
  const int blk = blockIdx.x * 32;
  const uint4* base = (const uint4*)X;

  // ---- gather phase: 2 sweeps x 16 nodes
#pragma unroll
  for (int s2 = 0; s2 < 2; ++s2) {
    int nl = s2 * 16 + g;
    int node = blk + nl;
    float s[8] = {0, 0, 0, 0, 0, 0, 0, 0};
    if (node < M) {
      add8(s, base[(size_t)node * 16 + l]);
      int c = cnt[node];
      const int* sl = slots + ((size_t)node << 7);
      int idx = sl[l];                 // coalesced: 16 indices per group
      int cc = (c < 16) ? c : 16;
      int j = 0;
      for (; j + 4 <= cc; j += 4) {
        int i0 = __shfl(idx, gb + j + 0, 64);
        int i1 = __shfl(idx, gb + j + 1, 64);
        int i2 = __shfl(idx, gb + j + 2, 64);
        int i3 = __shfl(idx, gb + j + 3, 64);
        uint4 v0 = base[(size_t)i0 * 16 + l];
        uint4 v1 = base[(size_t)i1 * 16 + l];
        uint4 v2 = base[(size_t)i2 * 16 + l];
        uint4 v3 = base[(size_t)i3 * 16 + l];
        add8(s, v0); add8(s, v1); add8(s, v2); add8(s, v3);
      }
      for (; j < cc; ++j) {
        int ij = __shfl(idx, gb + j, 64);
        add8(s, base[(size_t)ij * 16 + l]);
      }
      if (c > 16) {                    // ~10% of nodes at mean degree 12
        int idx2 = sl[16 + l];
        int cc2 = (c < 32) ? c : 32;
        for (j = 16; j + 4 <= cc2; j += 4) {
          int i0 = __shfl(idx2, gb + (j - 16) + 0, 64);
          int i1 = __shfl(idx2, gb + (j - 16) + 1, 64);
          int i2 = __shfl(idx2, gb + (j - 16) + 2, 64);
          int i3 = __shfl(idx2, gb + (j - 16) + 3, 64);
          uint4 v0 = base[(size_t)i0 * 16 + l];
          uint4 v1 = base[(size_t)i1 * 16 + l];
          uint4 v2 = base[(size_t)i2 * 16 + l];
          uint4 v3 = base[(size_t)i3 * 16 + l];
          add8(s, v0); add8(s, v1); add8(s, v2); add8(s, v3);
        }
        for (; j < cc2; ++j) {
          int ij = __shfl(idx2, gb + (j - 16), 64);
          add8(s, base[(size_t)ij * 16 + l]);
        }
        for (j = 32; j < c; ++j)       // astronomically rare
          add8(s, base[(size_t)sl[j] * 16 + l]);
      }
    }
    uint4 o;
    o.x = pack2(s[0], s[1]); o.y = pack2(s[2], s[3]);
    o.z = pack2(s[4], s[5]); o.w = pack2(s[6], s[7]);
    *(uint4*)&As[nl * 136 + l * 8] = o;
  }
  __syncthreads();

  // ---- MFMA phase: 4 waves 2x2; wave tile 16m x 64n
  const int w = tid >> 6;
  const int wm = w & 1, wn = w >> 1;
  const int l15 = lane & 15, quad = lane >> 4;
  const int mb = wm * 16, nb2 = wn * 64;

  const unsigned short* bp[4];
#pragma unroll
  for (int nf = 0; nf < 4; ++nf)
    bp[nf] = BT + (size_t)(nb2 + nf * 16 + l15) * 128 + quad * 8;

  v4f acc[4];
#pragma unroll
  for (int nf = 0; nf < 4; ++nf) acc[nf] = (v4f)0.f;

#pragma unroll
  for (int k0 = 0; k0 < 128; k0 += 32) {
    short8 a = *(const short8*)&As[(mb + l15) * 136 + k0 + quad * 8];
#pragma unroll
    for (int nf = 0; nf < 4; ++nf) {
      short8 b = *(const short8*)(bp[nf] + k0);
      acc[nf] = __builtin_amdgcn_mfma_f32_16x16x32_bf16(a, b, acc[nf], 0, 0, 0);
    }
  }

#pragma unroll
  for (int r = 0; r < 4; ++r) {
    int grow = blk + mb + quad * 4 + r;
    if (grow >= M) continue;
#pragma unroll
    for (int nf = 0; nf < 4; ++nf) {
      int gcol = nb2 + nf * 16 + l15;
      float v = acc[nf][r] + bias[gcol];
      C[(size_t)grow * 128 + gcol] = f2bf(fmaxf(v, 0.f));
    }
  }
}

// ------------------------- fused MLP head ----------------------------------
// Per 64-row block: Hs[64,256] = relu(A @ Wm1T^T + bm1) staged in LDS,
// then out[64,10] = Hs @ Wm2T^T + bm2 (Wm2T zero-padded to 16 cols).
__global__ __launch_bounds__(256) void fused_head(
    const unsigned short* __restrict__ A, const unsigned short* __restrict__ W1T,
    const float* __restrict__ b1, const unsigned short* __restrict__ W2T,
    const float* __restrict__ b2, float* __restrict__ out, int M, int NOUT) {
  __shared__ __align__(16) unsigned short Hs[64 * 264];  // 256 + 8 pad
  const int tid = threadIdx.x, lane = tid & 63, w = tid >> 6;
  const int l15 = lane & 15, quad = lane >> 4;
  const int blk = blockIdx.x * 64;

  // ---- phase A: 64x256 GEMM (K=128), waves 2x2, wave 32m x 128n
  const int wm = w & 1, wn = w >> 1;
  const int mb = wm * 32, nb = wn * 128;
  const unsigned short* ap[2];
#pragma unroll
  for (int mf = 0; mf < 2; ++mf) {
    int r = blk + mb + mf * 16 + l15;
    if (r > M - 1) r = M - 1;
    ap[mf] = A + (size_t)r * 128 + quad * 8;
  }
  v4f acc[2][8];
#pragma unroll
  for (int mf = 0; mf < 2; ++mf)
#pragma unroll
    for (int nf = 0; nf < 8; ++nf) acc[mf][nf] = (v4f)0.f;

#pragma unroll
  for (int k0 = 0; k0 < 128; k0 += 32) {
    short8 a[2];
#pragma unroll
    for (int mf = 0; mf < 2; ++mf) a[mf] = *(const short8*)(ap[mf] + k0);
#pragma unroll
    for (int nf = 0; nf < 8; ++nf) {
      short8 b = *(const short8*)(W1T + (size_t)(nb + nf * 16 + l15) * 128 + quad * 8 + k0);
#pragma unroll
      for (int mf = 0; mf < 2; ++mf)
        acc[mf][nf] = __builtin_amdgcn_mfma_f32_16x16x32_bf16(a[mf], b, acc[mf][nf], 0, 0, 0);
    }
  }
#pragma unroll
  for (int mf = 0; mf < 2; ++mf)
#pragma unroll
    for (int r = 0; r < 4; ++r) {
      int row = mb + mf * 16 + quad * 4 + r;
#pragma unroll
      for (int nf = 0; nf < 8; ++nf) {
        int col = nb + nf * 16 + l15;
        float v = acc[mf][nf][r] + b1[col];
        Hs[row * 264 + col] = f2bf(fmaxf(v, 0.f));
      }
    }
  __syncthreads();

  // ---- phase B: 64x16 GEMM (K=256) from LDS; wave handles 16 rows
  const int rowl = w * 16 + l15;
  const unsigned short* bp2 = W2T + (size_t)l15 * 256 + quad * 8;
  v4f acc2 = (v4f)0.f;
#pragma unroll
  for (int k0 = 0; k0 < 256; k0 += 32)
    acc2 = __builtin_amdgcn_mfma_f32_16x16x32_bf16(
        *(const short8*)&Hs[rowl * 264 + k0 + quad * 8],
        *(const short8*)(bp2 + k0), acc2, 0, 0, 0);
  float bb = (l15 < NOUT) ? b2[l15] : 0.f;
#pragma unroll
  for (int r = 0; r < 4; ++r) {
    int grow = blk + w * 16 + quad * 4 + r;
    if (grow < M && l15 < NOUT) out[(size_t)grow * NOUT + l15] = acc2[r] + bb;
  }
}

// ---------------------------------------------------------------------------

extern "C" void kernel_launch(void* const* d_in, const int* in_sizes, int n_in,
                              void* d_out, int out_size, void* d_ws, size_t ws_size,
                              hipStream_t stream) {
  const float* x   = (const float*)d_in[0];
  const int*   ei  = (const int*)d_in[1];
  const float* W0  = (const float*)d_in[2];
  const float* b0  = (const float*)d_in[3];
  const float* W1  = (const float*)d_in[4];
  const float* b1  = (const float*)d_in[5];
  const float* W2  = (const float*)d_in[6];
  const float* b2  = (const float*)d_in[7];
  const float* Wm1 = (const float*)d_in[8];
  const float* bm1 = (const float*)d_in[9];
  const float* Wm2 = (const float*)d_in[10];
  const float* bm2 = (const float*)d_in[11];
  float* out = (float*)d_out;

  const int D = 128;
  const int N = in_sizes[0] / D;   // 50000
  const int E = in_sizes[1] / 2;   // 600000
  const int L = in_sizes[11];      // 10

  const int* srcv = ei;
  const int* dstv = ei + E;

  char* ws = (char*)d_ws;
  size_t off = 0;
  auto alloc = [&](size_t bytes) -> void* {
    void* p = ws + off;
    off = (off + bytes + 255) & ~(size_t)255;
    return p;
  };
  int* cursor = (int*)alloc((size_t)N * 4);
  int* slots  = (int*)alloc((size_t)N * 128 * 4);
  unsigned short* xb   = (unsigned short*)alloc((size_t)N * 128 * 2);
  unsigned short* h1   = (unsigned short*)alloc((size_t)N * 128 * 2);
  unsigned short* h2   = (unsigned short*)alloc((size_t)N * 128 * 2);
  unsigned short* W0T  = (unsigned short*)alloc(128 * 128 * 2);
  unsigned short* W1T  = (unsigned short*)alloc(128 * 128 * 2);
  unsigned short* W2T  = (unsigned short*)alloc(128 * 128 * 2);
  unsigned short* Wm1T = (unsigned short*)alloc(256 * 128 * 2);
  unsigned short* Wm2T = (unsigned short*)alloc(16 * 256 * 2);
  (void)ws_size; (void)n_in; (void)out_size;

  const int tpb = 256;
  prep_weights<<<dim3(336), dim3(tpb), 0, stream>>>(W0, W1, W2, Wm1, Wm2,
                                                    W0T, W1T, W2T, Wm1T, Wm2T,
                                                    cursor, N);
  int n8 = N * 16;
  int big = (n8 > E) ? n8 : E;
  f2b_fill<<<dim3((big + tpb - 1) / tpb), dim3(tpb), 0, stream>>>(
      x, xb, n8, srcv, dstv, cursor, slots, E);

  dim3 lgrid((N + 31) / 32);
  dim3 hgrid((N + 63) / 64);
  fused_layer<<<lgrid, dim3(tpb), 0, stream>>>(xb, cursor, slots, W0T, b0, h1, N);
  fused_layer<<<lgrid, dim3(tpb), 0, stream>>>(h1, cursor, slots, W1T, b1, h2, N);
  fused_layer<<<lgrid, dim3(tpb), 0, stream>>>(h2, cursor, slots, W2T, b2, h1, N);
  fused_head<<<hgrid, dim3(tpb), 0, stream>>>(h1, Wm1T, bm1, Wm2T, bm2, out, N, L);
}

// Round 5
// 248.746 us; speedup vs baseline: 1.1519x; 1.1519x over previous
//
#include <hip/hip_runtime.h>

// ---------------------------------------------------------------------------
// GIN: 3 x (bucket gather-sum + (x+agg)@W + b, relu) + MLP head, bf16 MFMA.
// r5: - slot scatter (54us, 35MB write-amp) replaced by 64-node-bucket
//       binning: LDS histogram + per-(block,bucket) reserve -> contiguous
//       segment writes (L2-hot). 782 buckets == the 782 layer tiles.
//     - fused_layer counting-sorts its bucket in LDS; src indices become
//       LDS broadcast reads; row gather runs an 8-deep independent-load
//       pipeline (~6KB/CU in flight vs ~1KB before).
//     - 6 dispatches: prep_all, bin_edges, 3x fused_layer, fused_head.
// ---------------------------------------------------------------------------

typedef short short8 __attribute__((ext_vector_type(8)));
typedef float v4f __attribute__((ext_vector_type(4)));

#define BCAP 1024   // bucket capacity: avg 768 edges, +9 sigma head-room
#define MAXB 1024   // LDS histogram size in bin_edges (>= nbuckets=782)

__device__ inline unsigned short f2bf(float f) {
  union { float f; unsigned int u; } c; c.f = f;
  unsigned int u = c.u;
  return (unsigned short)((u + 0x7fffu + ((u >> 16) & 1u)) >> 16);  // RNE
}
__device__ inline float bfbits2f(unsigned int hi) {
  union { unsigned int u; float f; } c; c.u = hi; return c.f;
}
__device__ inline unsigned int pack2(float a, float b) {
  return (unsigned int)f2bf(a) | ((unsigned int)f2bf(b) << 16);
}
__device__ inline void add8(float* s, uint4 v) {
  s[0] += bfbits2f(v.x << 16); s[1] += bfbits2f(v.x & 0xffff0000u);
  s[2] += bfbits2f(v.y << 16); s[3] += bfbits2f(v.y & 0xffff0000u);
  s[4] += bfbits2f(v.z << 16); s[5] += bfbits2f(v.z & 0xffff0000u);
  s[6] += bfbits2f(v.w << 16); s[7] += bfbits2f(v.w & 0xffff0000u);
}
__device__ inline int wave_incl_scan_int(int v, int lane) {
#pragma unroll
  for (int off = 1; off < 64; off <<= 1) {
    int t = __shfl_up(v, off, 64);
    if (lane >= off) v += t;
  }
  return v;
}

// ------------------------- prep: weights + x->bf16 + zero bcnt --------------
__global__ __launch_bounds__(256) void prep_all(
    const float* __restrict__ W0, const float* __restrict__ W1, const float* __restrict__ W2,
    const float* __restrict__ Wm1, const float* __restrict__ Wm2,
    unsigned short* __restrict__ W0T, unsigned short* __restrict__ W1T,
    unsigned short* __restrict__ W2T, unsigned short* __restrict__ Wm1T,
    unsigned short* __restrict__ Wm2T,
    const float* __restrict__ x, unsigned short* __restrict__ xb, int n8,
    int* __restrict__ bcnt) {
  int i = blockIdx.x * 256 + threadIdx.x;
  if (i < MAXB) bcnt[i] = 0;
  if (i < n8) {
    const float4* p = (const float4*)x;
    float4 a = p[2 * (size_t)i], b = p[2 * (size_t)i + 1];
    uint4 o;
    o.x = pack2(a.x, a.y); o.y = pack2(a.z, a.w);
    o.z = pack2(b.x, b.y); o.w = pack2(b.z, b.w);
    ((uint4*)xb)[i] = o;
  }
  if (i < 49152) {                       // 3 x [128,128] -> [128n][128k]
    int w = i / 16384, r = i % 16384;
    int nn = r >> 7, k = r & 127;
    const float* W = (w == 0) ? W0 : (w == 1) ? W1 : W2;
    unsigned short* O = (w == 0) ? W0T : (w == 1) ? W1T : W2T;
    O[r] = f2bf(W[k * 128 + nn]);
  } else if (i < 49152 + 32768) {        // Wm1 [128,256] -> [256n][128k]
    int r = i - 49152;
    int nn = r >> 7, k = r & 127;
    Wm1T[r] = f2bf(Wm1[k * 256 + nn]);
  } else if (i < 49152 + 32768 + 4096) { // Wm2 [256,10] -> [16n][256k], pad 0
    int r = i - 49152 - 32768;
    int nn = r >> 8, k = r & 255;
    Wm2T[r] = (nn < 10) ? f2bf(Wm2[k * 10 + nn]) : (unsigned short)0;
  }
}

// ------------------------- bin edges into 64-node buckets -------------------
// entry = (src << 6) | (dst & 63); bucket = dst >> 6.
// 64 blocks; per-block LDS histogram -> one global reserve per (block,bucket)
// -> contiguous segment writes (lines stay hot in L2 during the block).
__global__ __launch_bounds__(256) void bin_edges(
    const int* __restrict__ src, const int* __restrict__ dst, int E, int per,
    int* __restrict__ bcnt, int* __restrict__ bucketA, int nbuckets) {
  __shared__ int hist[MAXB];
  __shared__ int base[MAXB];
  const int tid = threadIdx.x;
  const int e0 = blockIdx.x * per;
  const int e1 = (e0 + per < E) ? e0 + per : E;
  for (int j = tid; j < nbuckets; j += 256) hist[j] = 0;
  __syncthreads();
  for (int i = e0 + tid; i < e1; i += 256) atomicAdd(&hist[dst[i] >> 6], 1);
  __syncthreads();
  for (int j = tid; j < nbuckets; j += 256) {
    int h = hist[j];
    base[j] = h ? atomicAdd(&bcnt[j], h) : 0;
  }
  __syncthreads();
  for (int i = e0 + tid; i < e1; i += 256) {
    int d = dst[i], s = src[i];
    int b = d >> 6;
    int r = atomicAdd(&base[b], 1);  // bumps from reserved base
    bucketA[(size_t)b * BCAP + r] = (s << 6) | (d & 63);
  }
}

// ------------------------- fused layer --------------------------------------
// Block = bucket = 64 nodes. Load bucket -> LDS counting sort by local node
// -> per-node src lists in LDS -> 8-deep pipelined row gather -> MFMA.
__global__ __launch_bounds__(256) void fused_layer(
    const unsigned short* __restrict__ X, const int* __restrict__ bcnt,
    const int* __restrict__ bucketA, const unsigned short* __restrict__ BT,
    const float* __restrict__ bias, unsigned short* __restrict__ C, int M) {
  __shared__ __align__(16) unsigned short As[64 * 136];  // 17.4KB; rawE aliased
  __shared__ int srcS[BCAP];
  __shared__ int offs[65];
  __shared__ int cur[64];
  __shared__ int hist[64];
  const int tid = threadIdx.x;
  const int lane = tid & 63;
  const int b = blockIdx.x;
  const int blk = b * 64;
  const int cntb = bcnt[b];
  int* rawE = (int*)As;

  // ---- load bucket + counting sort by local node
  for (int i = tid; i < cntb; i += 256) rawE[i] = bucketA[(size_t)b * BCAP + i];
  if (tid < 64) hist[tid] = 0;
  __syncthreads();
  for (int i = tid; i < cntb; i += 256) atomicAdd(&hist[rawE[i] & 63], 1);
  __syncthreads();
  if (tid < 64) {
    int v = hist[tid];
    int incl = wave_incl_scan_int(v, lane);
    offs[tid] = incl - v;
    cur[tid] = incl - v;
    if (tid == 63) offs[64] = incl;
  }
  __syncthreads();
  for (int i = tid; i < cntb; i += 256) {
    int e = rawE[i];
    int p = atomicAdd(&cur[e & 63], 1);
    srcS[p] = e >> 6;
  }
  __syncthreads();  // rawE (As) free after this point

  // ---- gather: 4 sweeps x 16 nodes; 16 lanes x 16B per row; 8-deep loads
  const int l = tid & 15, g = tid >> 4;
  const uint4* base = (const uint4*)X;
#pragma unroll
  for (int s2 = 0; s2 < 4; ++s2) {
    int nl = s2 * 16 + g;
    int node = blk + nl;
    float s[8] = {0, 0, 0, 0, 0, 0, 0, 0};
    if (node < M) {
      add8(s, base[(size_t)node * 16 + l]);
      int beg = offs[nl], c = offs[nl + 1] - beg;
      int j = 0;
      for (; j + 8 <= c; j += 8) {
        int i0 = srcS[beg + j + 0], i1 = srcS[beg + j + 1];
        int i2 = srcS[beg + j + 2], i3 = srcS[beg + j + 3];
        int i4 = srcS[beg + j + 4], i5 = srcS[beg + j + 5];
        int i6 = srcS[beg + j + 6], i7 = srcS[beg + j + 7];
        uint4 v0 = base[(size_t)i0 * 16 + l];
        uint4 v1 = base[(size_t)i1 * 16 + l];
        uint4 v2 = base[(size_t)i2 * 16 + l];
        uint4 v3 = base[(size_t)i3 * 16 + l];
        uint4 v4 = base[(size_t)i4 * 16 + l];
        uint4 v5 = base[(size_t)i5 * 16 + l];
        uint4 v6 = base[(size_t)i6 * 16 + l];
        uint4 v7 = base[(size_t)i7 * 16 + l];
        add8(s, v0); add8(s, v1); add8(s, v2); add8(s, v3);
        add8(s, v4); add8(s, v5); add8(s, v6); add8(s, v7);
      }
      if (j + 4 <= c) {
        int i0 = srcS[beg + j + 0], i1 = srcS[beg + j + 1];
        int i2 = srcS[beg + j + 2], i3 = srcS[beg + j + 3];
        uint4 v0 = base[(size_t)i0 * 16 + l];
        uint4 v1 = base[(size_t)i1 * 16 + l];
        uint4 v2 = base[(size_t)i2 * 16 + l];
        uint4 v3 = base[(size_t)i3 * 16 + l];
        add8(s, v0); add8(s, v1); add8(s, v2); add8(s, v3);
        j += 4;
      }
      if (j + 2 <= c) {
        int i0 = srcS[beg + j + 0], i1 = srcS[beg + j + 1];
        uint4 v0 = base[(size_t)i0 * 16 + l];
        uint4 v1 = base[(size_t)i1 * 16 + l];
        add8(s, v0); add8(s, v1);
        j += 2;
      }
      if (j < c) add8(s, base[(size_t)srcS[beg + j] * 16 + l]);
    }
    uint4 o;
    o.x = pack2(s[0], s[1]); o.y = pack2(s[2], s[3]);
    o.z = pack2(s[4], s[5]); o.w = pack2(s[6], s[7]);
    __syncthreads();  // ensure all scatter/sort readers done before 1st write
    *(uint4*)&As[nl * 136 + l * 8] = o;
  }
  __syncthreads();

  // ---- MFMA phase: 4 waves 2x2; wave tile 32m x 64n; K=128
  const int w = tid >> 6;
  const int wm = w & 1, wn = w >> 1;
  const int l15 = lane & 15, quad = lane >> 4;
  const int mb = wm * 32, nb2 = wn * 64;

  const unsigned short* bp[4];
#pragma unroll
  for (int nf = 0; nf < 4; ++nf)
    bp[nf] = BT + (size_t)(nb2 + nf * 16 + l15) * 128 + quad * 8;

  v4f acc[2][4];
#pragma unroll
  for (int mf = 0; mf < 2; ++mf)
#pragma unroll
    for (int nf = 0; nf < 4; ++nf) acc[mf][nf] = (v4f)0.f;

#pragma unroll
  for (int k0 = 0; k0 < 128; k0 += 32) {
    short8 a[2], bv[4];
#pragma unroll
    for (int mf = 0; mf < 2; ++mf)
      a[mf] = *(const short8*)&As[(mb + mf * 16 + l15) * 136 + k0 + quad * 8];
#pragma unroll
    for (int nf = 0; nf < 4; ++nf) bv[nf] = *(const short8*)(bp[nf] + k0);
#pragma unroll
    for (int mf = 0; mf < 2; ++mf)
#pragma unroll
      for (int nf = 0; nf < 4; ++nf)
        acc[mf][nf] = __builtin_amdgcn_mfma_f32_16x16x32_bf16(a[mf], bv[nf], acc[mf][nf], 0, 0, 0);
  }

#pragma unroll
  for (int mf = 0; mf < 2; ++mf) {
#pragma unroll
    for (int r = 0; r < 4; ++r) {
      int grow = blk + mb + mf * 16 + quad * 4 + r;
      if (grow >= M) continue;
#pragma unroll
      for (int nf = 0; nf < 4; ++nf) {
        int gcol = nb2 + nf * 16 + l15;
        float v = acc[mf][nf][r] + bias[gcol];
        C[(size_t)grow * 128 + gcol] = f2bf(fmaxf(v, 0.f));
      }
    }
  }
}

// ------------------------- fused MLP head ----------------------------------
__global__ __launch_bounds__(256) void fused_head(
    const unsigned short* __restrict__ A, const unsigned short* __restrict__ W1T,
    const float* __restrict__ b1, const unsigned short* __restrict__ W2T,
    const float* __restrict__ b2, float* __restrict__ out, int M, int NOUT) {
  __shared__ __align__(16) unsigned short Hs[64 * 264];  // 256 + 8 pad
  const int tid = threadIdx.x, lane = tid & 63, w = tid >> 6;
  const int l15 = lane & 15, quad = lane >> 4;
  const int blk = blockIdx.x * 64;

  // ---- phase A: 64x256 GEMM (K=128), waves 2x2, wave 32m x 128n
  const int wm = w & 1, wn = w >> 1;
  const int mb = wm * 32, nb = wn * 128;
  const unsigned short* ap[2];
#pragma unroll
  for (int mf = 0; mf < 2; ++mf) {
    int r = blk + mb + mf * 16 + l15;
    if (r > M - 1) r = M - 1;
    ap[mf] = A + (size_t)r * 128 + quad * 8;
  }
  v4f acc[2][8];
#pragma unroll
  for (int mf = 0; mf < 2; ++mf)
#pragma unroll
    for (int nf = 0; nf < 8; ++nf) acc[mf][nf] = (v4f)0.f;

#pragma unroll
  for (int k0 = 0; k0 < 128; k0 += 32) {
    short8 a[2];
#pragma unroll
    for (int mf = 0; mf < 2; ++mf) a[mf] = *(const short8*)(ap[mf] + k0);
#pragma unroll
    for (int nf = 0; nf < 8; ++nf) {
      short8 bb = *(const short8*)(W1T + (size_t)(nb + nf * 16 + l15) * 128 + quad * 8 + k0);
#pragma unroll
      for (int mf = 0; mf < 2; ++mf)
        acc[mf][nf] = __builtin_amdgcn_mfma_f32_16x16x32_bf16(a[mf], bb, acc[mf][nf], 0, 0, 0);
    }
  }
#pragma unroll
  for (int mf = 0; mf < 2; ++mf)
#pragma unroll
    for (int r = 0; r < 4; ++r) {
      int row = mb + mf * 16 + quad * 4 + r;
#pragma unroll
      for (int nf = 0; nf < 8; ++nf) {
        int col = nb + nf * 16 + l15;
        float v = acc[mf][nf][r] + b1[col];
        Hs[row * 264 + col] = f2bf(fmaxf(v, 0.f));
      }
    }
  __syncthreads();

  // ---- phase B: 64x16 GEMM (K=256) from LDS; wave handles 16 rows
  const int rowl = w * 16 + l15;
  const unsigned short* bp2 = W2T + (size_t)l15 * 256 + quad * 8;
  v4f acc2 = (v4f)0.f;
#pragma unroll
  for (int k0 = 0; k0 < 256; k0 += 32)
    acc2 = __builtin_amdgcn_mfma_f32_16x16x32_bf16(
        *(const short8*)&Hs[rowl * 264 + k0 + quad * 8],
        *(const short8*)(bp2 + k0), acc2, 0, 0, 0);
  float bb = (l15 < NOUT) ? b2[l15] : 0.f;
#pragma unroll
  for (int r = 0; r < 4; ++r) {
    int grow = blk + w * 16 + quad * 4 + r;
    if (grow < M && l15 < NOUT) out[(size_t)grow * NOUT + l15] = acc2[r] + bb;
  }
}

// ---------------------------------------------------------------------------

extern "C" void kernel_launch(void* const* d_in, const int* in_sizes, int n_in,
                              void* d_out, int out_size, void* d_ws, size_t ws_size,
                              hipStream_t stream) {
  const float* x   = (const float*)d_in[0];
  const int*   ei  = (const int*)d_in[1];
  const float* W0  = (const float*)d_in[2];
  const float* b0  = (const float*)d_in[3];
  const float* W1  = (const float*)d_in[4];
  const float* b1  = (const float*)d_in[5];
  const float* W2  = (const float*)d_in[6];
  const float* b2  = (const float*)d_in[7];
  const float* Wm1 = (const float*)d_in[8];
  const float* bm1 = (const float*)d_in[9];
  const float* Wm2 = (const float*)d_in[10];
  const float* bm2 = (const float*)d_in[11];
  float* out = (float*)d_out;

  const int D = 128;
  const int N = in_sizes[0] / D;   // 50000
  const int E = in_sizes[1] / 2;   // 600000
  const int L = in_sizes[11];      // 10
  const int nb = (N + 63) / 64;    // 782 buckets == layer tiles

  const int* srcv = ei;
  const int* dstv = ei + E;

  char* ws = (char*)d_ws;
  size_t off = 0;
  auto alloc = [&](size_t bytes) -> void* {
    void* p = ws + off;
    off = (off + bytes + 255) & ~(size_t)255;
    return p;
  };
  int* bcnt    = (int*)alloc((size_t)MAXB * 4);
  int* bucketA = (int*)alloc((size_t)nb * BCAP * 4);
  unsigned short* xb   = (unsigned short*)alloc((size_t)N * 128 * 2);
  unsigned short* h1   = (unsigned short*)alloc((size_t)N * 128 * 2);
  unsigned short* h2   = (unsigned short*)alloc((size_t)N * 128 * 2);
  unsigned short* W0T  = (unsigned short*)alloc(128 * 128 * 2);
  unsigned short* W1T  = (unsigned short*)alloc(128 * 128 * 2);
  unsigned short* W2T  = (unsigned short*)alloc(128 * 128 * 2);
  unsigned short* Wm1T = (unsigned short*)alloc(256 * 128 * 2);
  unsigned short* Wm2T = (unsigned short*)alloc(16 * 256 * 2);
  (void)ws_size; (void)n_in; (void)out_size;

  const int tpb = 256;
  int n8 = N * 16;
  prep_all<<<dim3((n8 + tpb - 1) / tpb), dim3(tpb), 0, stream>>>(
      W0, W1, W2, Wm1, Wm2, W0T, W1T, W2T, Wm1T, Wm2T, x, xb, n8, bcnt);

  const int nbin = 64;                     // binning blocks
  int per = (E + nbin - 1) / nbin;
  bin_edges<<<dim3(nbin), dim3(tpb), 0, stream>>>(srcv, dstv, E, per, bcnt, bucketA, nb);

  dim3 lgrid(nb);
  fused_layer<<<lgrid, dim3(tpb), 0, stream>>>(xb, bcnt, bucketA, W0T, b0, h1, N);
  fused_layer<<<lgrid, dim3(tpb), 0, stream>>>(h1, bcnt, bucketA, W1T, b1, h2, N);
  fused_layer<<<lgrid, dim3(tpb), 0, stream>>>(h2, bcnt, bucketA, W2T, b2, h1, N);
  fused_head<<<lgrid, dim3(tpb), 0, stream>>>(h1, Wm1T, bm1, Wm2T, bm2, out, N, L);
}

// Round 6
// 241.113 us; speedup vs baseline: 1.1884x; 1.0317x over previous
//
#include <hip/hip_runtime.h>

// ---------------------------------------------------------------------------
// GIN: 3 x (bucket gather-sum + (x+agg)@W + b, relu) + MLP head, bf16 MFMA.
// r6: - counting sort hoisted out of the layers (done once in sort_buckets);
//       layers stream sorted src lists into LDS -> NO barriers in the gather
//       loop (r5 had a redundant in-loop __syncthreads serializing sweeps).
//     - MLP head fused into layer 3 (As/Hs LDS union) -> saves 12.8MB
//       round-trip + a dispatch.
//     - bin_edges on 128 blocks (was 64 -> only 1/4 of CUs).
//     6 dispatches: prep_all, bin_edges, sort_buckets, 2x fused_layer,
//     fused_l3_head.
// ---------------------------------------------------------------------------

typedef short short8 __attribute__((ext_vector_type(8)));
typedef float v4f __attribute__((ext_vector_type(4)));

#define BCAP 1024   // bucket capacity: avg 768 edges, +9 sigma head-room
#define MAXB 1024   // >= nbuckets (782)

__device__ inline unsigned short f2bf(float f) {
  union { float f; unsigned int u; } c; c.f = f;
  unsigned int u = c.u;
  return (unsigned short)((u + 0x7fffu + ((u >> 16) & 1u)) >> 16);  // RNE
}
__device__ inline float bfbits2f(unsigned int hi) {
  union { unsigned int u; float f; } c; c.u = hi; return c.f;
}
__device__ inline unsigned int pack2(float a, float b) {
  return (unsigned int)f2bf(a) | ((unsigned int)f2bf(b) << 16);
}
__device__ inline void add8(float* s, uint4 v) {
  s[0] += bfbits2f(v.x << 16); s[1] += bfbits2f(v.x & 0xffff0000u);
  s[2] += bfbits2f(v.y << 16); s[3] += bfbits2f(v.y & 0xffff0000u);
  s[4] += bfbits2f(v.z << 16); s[5] += bfbits2f(v.z & 0xffff0000u);
  s[6] += bfbits2f(v.w << 16); s[7] += bfbits2f(v.w & 0xffff0000u);
}
__device__ inline int wave_incl_scan_int(int v, int lane) {
#pragma unroll
  for (int off = 1; off < 64; off <<= 1) {
    int t = __shfl_up(v, off, 64);
    if (lane >= off) v += t;
  }
  return v;
}

// ------------------------- prep: weights + x->bf16 + zero bcnt --------------
__global__ __launch_bounds__(256) void prep_all(
    const float* __restrict__ W0, const float* __restrict__ W1, const float* __restrict__ W2,
    const float* __restrict__ Wm1, const float* __restrict__ Wm2,
    unsigned short* __restrict__ W0T, unsigned short* __restrict__ W1T,
    unsigned short* __restrict__ W2T, unsigned short* __restrict__ Wm1T,
    unsigned short* __restrict__ Wm2T,
    const float* __restrict__ x, unsigned short* __restrict__ xb, int n8,
    int* __restrict__ bcnt) {
  int i = blockIdx.x * 256 + threadIdx.x;
  if (i < MAXB) bcnt[i] = 0;
  if (i < n8) {
    const float4* p = (const float4*)x;
    float4 a = p[2 * (size_t)i], b = p[2 * (size_t)i + 1];
    uint4 o;
    o.x = pack2(a.x, a.y); o.y = pack2(a.z, a.w);
    o.z = pack2(b.x, b.y); o.w = pack2(b.z, b.w);
    ((uint4*)xb)[i] = o;
  }
  if (i < 49152) {                       // 3 x [128,128] -> [128n][128k]
    int w = i / 16384, r = i % 16384;
    int nn = r >> 7, k = r & 127;
    const float* W = (w == 0) ? W0 : (w == 1) ? W1 : W2;
    unsigned short* O = (w == 0) ? W0T : (w == 1) ? W1T : W2T;
    O[r] = f2bf(W[k * 128 + nn]);
  } else if (i < 49152 + 32768) {        // Wm1 [128,256] -> [256n][128k]
    int r = i - 49152;
    int nn = r >> 7, k = r & 127;
    Wm1T[r] = f2bf(Wm1[k * 256 + nn]);
  } else if (i < 49152 + 32768 + 4096) { // Wm2 [256,10] -> [16n][256k], pad 0
    int r = i - 49152 - 32768;
    int nn = r >> 8, k = r & 255;
    Wm2T[r] = (nn < 10) ? f2bf(Wm2[k * 10 + nn]) : (unsigned short)0;
  }
}

// ------------------------- bin edges into 64-node buckets -------------------
// entry = (src << 6) | (dst & 63); bucket = dst >> 6.
__global__ __launch_bounds__(256) void bin_edges(
    const int* __restrict__ src, const int* __restrict__ dst, int E, int per,
    int* __restrict__ bcnt, int* __restrict__ bucketA, int nbuckets) {
  __shared__ int hist[MAXB];
  __shared__ int base[MAXB];
  const int tid = threadIdx.x;
  const int e0 = blockIdx.x * per;
  const int e1 = (e0 + per < E) ? e0 + per : E;
  for (int j = tid; j < nbuckets; j += 256) hist[j] = 0;
  __syncthreads();
  for (int i = e0 + tid; i < e1; i += 256) atomicAdd(&hist[dst[i] >> 6], 1);
  __syncthreads();
  for (int j = tid; j < nbuckets; j += 256) {
    int h = hist[j];
    base[j] = h ? atomicAdd(&bcnt[j], h) : 0;
  }
  __syncthreads();
  for (int i = e0 + tid; i < e1; i += 256) {
    int d = dst[i], s = src[i];
    int b = d >> 6;
    int r = atomicAdd(&base[b], 1);
    bucketA[(size_t)b * BCAP + r] = (s << 6) | (d & 63);
  }
}

// ------------------------- per-bucket counting sort (once) ------------------
// Produces srcsS[b*BCAP + p] sorted by local node, boffs[b*65 + 0..64].
__global__ __launch_bounds__(256) void sort_buckets(
    const int* __restrict__ bcnt, const int* __restrict__ bucketA,
    int* __restrict__ srcsS, int* __restrict__ boffs) {
  __shared__ int rawE[BCAP];
  __shared__ int hist[64], cur[64], offs[65];
  const int tid = threadIdx.x;
  const int b = blockIdx.x;
  const int cnt = bcnt[b];
  for (int i = tid; i < cnt; i += 256) rawE[i] = bucketA[(size_t)b * BCAP + i];
  if (tid < 64) hist[tid] = 0;
  __syncthreads();
  for (int i = tid; i < cnt; i += 256) atomicAdd(&hist[rawE[i] & 63], 1);
  __syncthreads();
  if (tid < 64) {
    int v = hist[tid];
    int incl = wave_incl_scan_int(v, tid);
    offs[tid] = incl - v;
    cur[tid] = incl - v;
    if (tid == 63) offs[64] = incl;
  }
  __syncthreads();
  for (int i = tid; i < cnt; i += 256) {
    int e = rawE[i];
    int p = atomicAdd(&cur[e & 63], 1);
    srcsS[(size_t)b * BCAP + p] = e >> 6;   // 4KB hot region, L2-resident
  }
  if (tid < 65) boffs[b * 65 + tid] = offs[tid];
}

// ------------------------- fused layer (layers 1,2) -------------------------
// Block = bucket = 64 nodes. Stream sorted srcs -> LDS; barrier-free gather
// with deep load pipelining; MFMA 64x128 (2x2 waves, wave 32m x 64n, K=128).
__global__ __launch_bounds__(256) void fused_layer(
    const unsigned short* __restrict__ X, const int* __restrict__ bcnt,
    const int* __restrict__ srcsS, const int* __restrict__ boffs,
    const unsigned short* __restrict__ BT, const float* __restrict__ bias,
    unsigned short* __restrict__ C, int M) {
  __shared__ __align__(16) unsigned short As[64 * 136];
  __shared__ int srcS[BCAP];
  __shared__ int offs[65];
  const int tid = threadIdx.x;
  const int lane = tid & 63;
  const int b = blockIdx.x;
  const int blk = b * 64;
  const int cnt = bcnt[b];

  if (tid < 65) offs[tid] = boffs[b * 65 + tid];
  for (int i = tid; i < cnt; i += 256) srcS[i] = srcsS[(size_t)b * BCAP + i];
  __syncthreads();

  // ---- gather: 4 sweeps x 16 nodes; 16 lanes x 16B per row; NO barriers
  const int l = tid & 15, g = tid >> 4;
  const uint4* base = (const uint4*)X;
#pragma unroll
  for (int s2 = 0; s2 < 4; ++s2) {
    int nl = s2 * 16 + g;
    int node = blk + nl;
    float s[8] = {0, 0, 0, 0, 0, 0, 0, 0};
    if (node < M) {
      add8(s, base[(size_t)node * 16 + l]);
      int beg = offs[nl], c = offs[nl + 1] - beg;
      int j = 0;
      for (; j + 8 <= c; j += 8) {
        int i0 = srcS[beg + j + 0], i1 = srcS[beg + j + 1];
        int i2 = srcS[beg + j + 2], i3 = srcS[beg + j + 3];
        int i4 = srcS[beg + j + 4], i5 = srcS[beg + j + 5];
        int i6 = srcS[beg + j + 6], i7 = srcS[beg + j + 7];
        uint4 v0 = base[(size_t)i0 * 16 + l];
        uint4 v1 = base[(size_t)i1 * 16 + l];
        uint4 v2 = base[(size_t)i2 * 16 + l];
        uint4 v3 = base[(size_t)i3 * 16 + l];
        uint4 v4 = base[(size_t)i4 * 16 + l];
        uint4 v5 = base[(size_t)i5 * 16 + l];
        uint4 v6 = base[(size_t)i6 * 16 + l];
        uint4 v7 = base[(size_t)i7 * 16 + l];
        add8(s, v0); add8(s, v1); add8(s, v2); add8(s, v3);
        add8(s, v4); add8(s, v5); add8(s, v6); add8(s, v7);
      }
      if (j + 4 <= c) {
        int i0 = srcS[beg + j + 0], i1 = srcS[beg + j + 1];
        int i2 = srcS[beg + j + 2], i3 = srcS[beg + j + 3];
        uint4 v0 = base[(size_t)i0 * 16 + l];
        uint4 v1 = base[(size_t)i1 * 16 + l];
        uint4 v2 = base[(size_t)i2 * 16 + l];
        uint4 v3 = base[(size_t)i3 * 16 + l];
        add8(s, v0); add8(s, v1); add8(s, v2); add8(s, v3);
        j += 4;
      }
      if (j + 2 <= c) {
        int i0 = srcS[beg + j + 0], i1 = srcS[beg + j + 1];
        uint4 v0 = base[(size_t)i0 * 16 + l];
        uint4 v1 = base[(size_t)i1 * 16 + l];
        add8(s, v0); add8(s, v1);
        j += 2;
      }
      if (j < c) add8(s, base[(size_t)srcS[beg + j] * 16 + l]);
    }
    uint4 o;
    o.x = pack2(s[0], s[1]); o.y = pack2(s[2], s[3]);
    o.z = pack2(s[4], s[5]); o.w = pack2(s[6], s[7]);
    *(uint4*)&As[nl * 136 + l * 8] = o;
  }
  __syncthreads();

  // ---- MFMA: 4 waves 2x2; wave tile 32m x 64n; K=128
  const int w = tid >> 6;
  const int wm = w & 1, wn = w >> 1;
  const int l15 = lane & 15, quad = lane >> 4;
  const int mb = wm * 32, nb2 = wn * 64;

  const unsigned short* bp[4];
#pragma unroll
  for (int nf = 0; nf < 4; ++nf)
    bp[nf] = BT + (size_t)(nb2 + nf * 16 + l15) * 128 + quad * 8;

  v4f acc[2][4];
#pragma unroll
  for (int mf = 0; mf < 2; ++mf)
#pragma unroll
    for (int nf = 0; nf < 4; ++nf) acc[mf][nf] = (v4f)0.f;

#pragma unroll
  for (int k0 = 0; k0 < 128; k0 += 32) {
    short8 a[2], bv[4];
#pragma unroll
    for (int mf = 0; mf < 2; ++mf)
      a[mf] = *(const short8*)&As[(mb + mf * 16 + l15) * 136 + k0 + quad * 8];
#pragma unroll
    for (int nf = 0; nf < 4; ++nf) bv[nf] = *(const short8*)(bp[nf] + k0);
#pragma unroll
    for (int mf = 0; mf < 2; ++mf)
#pragma unroll
      for (int nf = 0; nf < 4; ++nf)
        acc[mf][nf] = __builtin_amdgcn_mfma_f32_16x16x32_bf16(a[mf], bv[nf], acc[mf][nf], 0, 0, 0);
  }

#pragma unroll
  for (int mf = 0; mf < 2; ++mf) {
#pragma unroll
    for (int r = 0; r < 4; ++r) {
      int grow = blk + mb + mf * 16 + quad * 4 + r;
      if (grow >= M) continue;
#pragma unroll
      for (int nf = 0; nf < 4; ++nf) {
        int gcol = nb2 + nf * 16 + l15;
        float v = acc[mf][nf][r] + bias[gcol];
        C[(size_t)grow * 128 + gcol] = f2bf(fmaxf(v, 0.f));
      }
    }
  }
}

// ------------------------- fused layer 3 + MLP head -------------------------
// Same gather+MFMA as fused_layer, then head entirely in LDS:
//   t  = relu((x+agg)@W2 + b2)      -> back into As
//   Hs = relu(t @ Wm1 + bm1)        -> Hs (aliases As+srcS)
//   out= Hs @ Wm2 + bm2             (Wm2T zero-padded to 16 cols)
__global__ __launch_bounds__(256) void fused_l3_head(
    const unsigned short* __restrict__ X, const int* __restrict__ bcnt,
    const int* __restrict__ srcsS, const int* __restrict__ boffs,
    const unsigned short* __restrict__ W2T, const float* __restrict__ b2,
    const unsigned short* __restrict__ Wm1T, const float* __restrict__ bm1,
    const unsigned short* __restrict__ Wm2T, const float* __restrict__ bm2,
    float* __restrict__ out, int M, int NOUT) {
  __shared__ __align__(16) unsigned char lds[64 * 264 * 2];  // Hs 33.8KB
  unsigned short* As = (unsigned short*)lds;                 // 17.4KB
  int* srcS = (int*)(lds + 64 * 136 * 2);                    // 4KB after As
  unsigned short* Hs = (unsigned short*)lds;                 // aliases both
  __shared__ int offs[65];
  const int tid = threadIdx.x;
  const int lane = tid & 63;
  const int b = blockIdx.x;
  const int blk = b * 64;
  const int cnt = bcnt[b];

  if (tid < 65) offs[tid] = boffs[b * 65 + tid];
  for (int i = tid; i < cnt; i += 256) srcS[i] = srcsS[(size_t)b * BCAP + i];
  __syncthreads();

  // ---- gather (same as fused_layer)
  const int l = tid & 15, g = tid >> 4;
  const uint4* base = (const uint4*)X;
#pragma unroll
  for (int s2 = 0; s2 < 4; ++s2) {
    int nl = s2 * 16 + g;
    int node = blk + nl;
    float s[8] = {0, 0, 0, 0, 0, 0, 0, 0};
    if (node < M) {
      add8(s, base[(size_t)node * 16 + l]);
      int beg = offs[nl], c = offs[nl + 1] - beg;
      int j = 0;
      for (; j + 8 <= c; j += 8) {
        int i0 = srcS[beg + j + 0], i1 = srcS[beg + j + 1];
        int i2 = srcS[beg + j + 2], i3 = srcS[beg + j + 3];
        int i4 = srcS[beg + j + 4], i5 = srcS[beg + j + 5];
        int i6 = srcS[beg + j + 6], i7 = srcS[beg + j + 7];
        uint4 v0 = base[(size_t)i0 * 16 + l];
        uint4 v1 = base[(size_t)i1 * 16 + l];
        uint4 v2 = base[(size_t)i2 * 16 + l];
        uint4 v3 = base[(size_t)i3 * 16 + l];
        uint4 v4 = base[(size_t)i4 * 16 + l];
        uint4 v5 = base[(size_t)i5 * 16 + l];
        uint4 v6 = base[(size_t)i6 * 16 + l];
        uint4 v7 = base[(size_t)i7 * 16 + l];
        add8(s, v0); add8(s, v1); add8(s, v2); add8(s, v3);
        add8(s, v4); add8(s, v5); add8(s, v6); add8(s, v7);
      }
      if (j + 4 <= c) {
        int i0 = srcS[beg + j + 0], i1 = srcS[beg + j + 1];
        int i2 = srcS[beg + j + 2], i3 = srcS[beg + j + 3];
        uint4 v0 = base[(size_t)i0 * 16 + l];
        uint4 v1 = base[(size_t)i1 * 16 + l];
        uint4 v2 = base[(size_t)i2 * 16 + l];
        uint4 v3 = base[(size_t)i3 * 16 + l];
        add8(s, v0); add8(s, v1); add8(s, v2); add8(s, v3);
        j += 4;
      }
      if (j + 2 <= c) {
        int i0 = srcS[beg + j + 0], i1 = srcS[beg + j + 1];
        uint4 v0 = base[(size_t)i0 * 16 + l];
        uint4 v1 = base[(size_t)i1 * 16 + l];
        add8(s, v0); add8(s, v1);
        j += 2;
      }
      if (j < c) add8(s, base[(size_t)srcS[beg + j] * 16 + l]);
    }
    uint4 o;
    o.x = pack2(s[0], s[1]); o.y = pack2(s[2], s[3]);
    o.z = pack2(s[4], s[5]); o.w = pack2(s[6], s[7]);
    *(uint4*)&As[nl * 136 + l * 8] = o;
  }
  __syncthreads();

  // ---- layer-3 MFMA: 64x128, K=128
  const int w = tid >> 6;
  const int wm = w & 1, wn = w >> 1;
  const int l15 = lane & 15, quad = lane >> 4;
  const int mb = wm * 32, nb2 = wn * 64;

  v4f acc[2][4];
#pragma unroll
  for (int mf = 0; mf < 2; ++mf)
#pragma unroll
    for (int nf = 0; nf < 4; ++nf) acc[mf][nf] = (v4f)0.f;

#pragma unroll
  for (int k0 = 0; k0 < 128; k0 += 32) {
    short8 a[2], bv[4];
#pragma unroll
    for (int mf = 0; mf < 2; ++mf)
      a[mf] = *(const short8*)&As[(mb + mf * 16 + l15) * 136 + k0 + quad * 8];
#pragma unroll
    for (int nf = 0; nf < 4; ++nf)
      bv[nf] = *(const short8*)(W2T + (size_t)(nb2 + nf * 16 + l15) * 128 + quad * 8 + k0);
#pragma unroll
    for (int mf = 0; mf < 2; ++mf)
#pragma unroll
      for (int nf = 0; nf < 4; ++nf)
        acc[mf][nf] = __builtin_amdgcn_mfma_f32_16x16x32_bf16(a[mf], bv[nf], acc[mf][nf], 0, 0, 0);
  }
  __syncthreads();  // all As reads done before rewrite

  // t = relu(acc + b2) -> back into As (local rows 0..63, cols 0..127)
#pragma unroll
  for (int mf = 0; mf < 2; ++mf)
#pragma unroll
    for (int r = 0; r < 4; ++r) {
      int row = mb + mf * 16 + quad * 4 + r;
#pragma unroll
      for (int nf = 0; nf < 4; ++nf) {
        int col = nb2 + nf * 16 + l15;
        As[row * 136 + col] = f2bf(fmaxf(acc[mf][nf][r] + b2[col], 0.f));
      }
    }
  __syncthreads();

  // ---- head phase A: Hm = relu(t @ Wm1 + bm1), 64x256, K=128
  const int nbH = wn * 128;
  v4f acc2[2][8];
#pragma unroll
  for (int mf = 0; mf < 2; ++mf)
#pragma unroll
    for (int nf = 0; nf < 8; ++nf) acc2[mf][nf] = (v4f)0.f;

#pragma unroll
  for (int k0 = 0; k0 < 128; k0 += 32) {
    short8 a[2];
#pragma unroll
    for (int mf = 0; mf < 2; ++mf)
      a[mf] = *(const short8*)&As[(mb + mf * 16 + l15) * 136 + k0 + quad * 8];
#pragma unroll
    for (int nf = 0; nf < 8; ++nf) {
      short8 bb = *(const short8*)(Wm1T + (size_t)(nbH + nf * 16 + l15) * 128 + quad * 8 + k0);
#pragma unroll
      for (int mf = 0; mf < 2; ++mf)
        acc2[mf][nf] = __builtin_amdgcn_mfma_f32_16x16x32_bf16(a[mf], bb, acc2[mf][nf], 0, 0, 0);
    }
  }
  __syncthreads();  // As reads done; Hs may overwrite

#pragma unroll
  for (int mf = 0; mf < 2; ++mf)
#pragma unroll
    for (int r = 0; r < 4; ++r) {
      int row = mb + mf * 16 + quad * 4 + r;
#pragma unroll
      for (int nf = 0; nf < 8; ++nf) {
        int col = nbH + nf * 16 + l15;
        Hs[row * 264 + col] = f2bf(fmaxf(acc2[mf][nf][r] + bm1[col], 0.f));
      }
    }
  __syncthreads();

  // ---- head phase B: out = Hs @ Wm2 + bm2; 64x16, K=256; wave = 16 rows
  const int rowl = w * 16 + l15;
  const unsigned short* bp2 = Wm2T + (size_t)l15 * 256 + quad * 8;
  v4f acc3 = (v4f)0.f;
#pragma unroll
  for (int k0 = 0; k0 < 256; k0 += 32)
    acc3 = __builtin_amdgcn_mfma_f32_16x16x32_bf16(
        *(const short8*)&Hs[rowl * 264 + k0 + quad * 8],
        *(const short8*)(bp2 + k0), acc3, 0, 0, 0);
  float bb = (l15 < NOUT) ? bm2[l15] : 0.f;
#pragma unroll
  for (int r = 0; r < 4; ++r) {
    int grow = blk + w * 16 + quad * 4 + r;
    if (grow < M && l15 < NOUT) out[(size_t)grow * NOUT + l15] = acc3[r] + bb;
  }
}

// ---------------------------------------------------------------------------

extern "C" void kernel_launch(void* const* d_in, const int* in_sizes, int n_in,
                              void* d_out, int out_size, void* d_ws, size_t ws_size,
                              hipStream_t stream) {
  const float* x   = (const float*)d_in[0];
  const int*   ei  = (const int*)d_in[1];
  const float* W0  = (const float*)d_in[2];
  const float* b0  = (const float*)d_in[3];
  const float* W1  = (const float*)d_in[4];
  const float* b1  = (const float*)d_in[5];
  const float* W2  = (const float*)d_in[6];
  const float* b2  = (const float*)d_in[7];
  const float* Wm1 = (const float*)d_in[8];
  const float* bm1 = (const float*)d_in[9];
  const float* Wm2 = (const float*)d_in[10];
  const float* bm2 = (const float*)d_in[11];
  float* out = (float*)d_out;

  const int D = 128;
  const int N = in_sizes[0] / D;   // 50000
  const int E = in_sizes[1] / 2;   // 600000
  const int L = in_sizes[11];      // 10
  const int nb = (N + 63) / 64;    // 782 buckets == layer tiles

  const int* srcv = ei;
  const int* dstv = ei + E;

  char* ws = (char*)d_ws;
  size_t off = 0;
  auto alloc = [&](size_t bytes) -> void* {
    void* p = ws + off;
    off = (off + bytes + 255) & ~(size_t)255;
    return p;
  };
  int* bcnt    = (int*)alloc((size_t)MAXB * 4);
  int* bucketA = (int*)alloc((size_t)nb * BCAP * 4);
  int* srcsS   = (int*)alloc((size_t)nb * BCAP * 4);
  int* boffs   = (int*)alloc((size_t)nb * 65 * 4);
  unsigned short* xb   = (unsigned short*)alloc((size_t)N * 128 * 2);
  unsigned short* h1   = (unsigned short*)alloc((size_t)N * 128 * 2);
  unsigned short* h2   = (unsigned short*)alloc((size_t)N * 128 * 2);
  unsigned short* W0T  = (unsigned short*)alloc(128 * 128 * 2);
  unsigned short* W1T  = (unsigned short*)alloc(128 * 128 * 2);
  unsigned short* W2T  = (unsigned short*)alloc(128 * 128 * 2);
  unsigned short* Wm1T = (unsigned short*)alloc(256 * 128 * 2);
  unsigned short* Wm2T = (unsigned short*)alloc(16 * 256 * 2);
  (void)ws_size; (void)n_in; (void)out_size;

  const int tpb = 256;
  int n8 = N * 16;
  prep_all<<<dim3((n8 + tpb - 1) / tpb), dim3(tpb), 0, stream>>>(
      W0, W1, W2, Wm1, Wm2, W0T, W1T, W2T, Wm1T, Wm2T, x, xb, n8, bcnt);

  const int nbin = 128;
  int per = (E + nbin - 1) / nbin;
  bin_edges<<<dim3(nbin), dim3(tpb), 0, stream>>>(srcv, dstv, E, per, bcnt, bucketA, nb);
  sort_buckets<<<dim3(nb), dim3(tpb), 0, stream>>>(bcnt, bucketA, srcsS, boffs);

  dim3 lgrid(nb);
  fused_layer<<<lgrid, dim3(tpb), 0, stream>>>(xb, bcnt, srcsS, boffs, W0T, b0, h1, N);
  fused_layer<<<lgrid, dim3(tpb), 0, stream>>>(h1, bcnt, srcsS, boffs, W1T, b1, h2, N);
  fused_l3_head<<<lgrid, dim3(tpb), 0, stream>>>(h2, bcnt, srcsS, boffs, W2T, b2,
                                                 Wm1T, bm1, Wm2T, bm2, out, N, L);
}